// Round 6
// baseline (129.587 us; speedup 1.0000x reference)
//
#include <hip/hip_runtime.h>
#include <hip/hip_bf16.h>
#include <cstdint>
#include <cstddef>

// ---------------- problem constants ----------------
#define HW 36864            // 192*192
#define QT 64               // queries per tile (M-tile)
#define KSC 64              // K-split slices
#define NCH 72              // accumulator channels (64 fea + 3 sq + 3 wn + 1 w + pad)
constexpr int SLICE  = HW / KSC;    // 576
constexpr int NCHUNK = SLICE / 64;  // 9

constexpr bool is_valid_px(int v, int u) {
  int a = 2 * u - 63, b = 2 * v - 63;
  return a * a + b * b < 1024;   // integer-exact (==1024 impossible for odd,odd)
}
constexpr int count_valid() {
  int n = 0;
  for (int v = 0; v < 64; ++v)
    for (int u = 0; u < 64; ++u)
      if (is_valid_px(v, u)) ++n;
  return n;
}
constexpr int NV  = count_valid();          // 812
constexpr int NQT = (NV + QT - 1) / QT;     // 13 tiles of 64
constexpr int NQP = NQT * QT;               // 832 padded queries

struct QTab { short idx[NQP]; };            // rank -> pixel (or -1 pad)
constexpr QTab make_qtab() {
  QTab t{};
  int n = 0;
  for (int p = 0; p < 4096; ++p) {
    int v = p >> 6, u = p & 63;
    if (is_valid_px(v, u)) { t.idx[n] = (short)p; ++n; }
  }
  for (int i = n; i < NQP; ++i) t.idx[i] = -1;
  return t;
}
__constant__ QTab g_qtab = make_qtab();

typedef short short8 __attribute__((ext_vector_type(8)));
typedef float f32x4  __attribute__((ext_vector_type(4)));

__device__ __forceinline__ unsigned short f2b(float f) {  // f32 -> bf16 RNE (scalar)
  unsigned int u = __float_as_uint(f);
  u += 0x7FFFu + ((u >> 16) & 1u);
  return (unsigned short)(u >> 16);
}
__device__ __forceinline__ ushort2 f2b2(float a, float b) {  // packed cvt
  __hip_bfloat162 h = __float22bfloat162_rn(make_float2(a, b));
  return *(ushort2*)&h;
}
__device__ __forceinline__ ushort4 f2b4(float4 v) {
  ushort4 r;
  *(ushort2*)&r.x = f2b2(v.x, v.y);
  *(ushort2*)&r.z = f2b2(v.z, v.w);
  return r;
}
__device__ __forceinline__ void pix2qn(int pix, float& x, float& y, float& z) {
  x = 0.f; y = 0.f; z = 0.f;
  if (pix >= 0) {
    int v = pix >> 6, u = pix & 63;
    float p = (float)(2 * u - 63) * (1.0f / 32.0f);
    float q = -(float)(2 * v - 63) * (1.0f / 32.0f);
    float d = 1.0f + p * p + q * q;
    x = 2.0f * p / d; y = 2.0f * q / d; z = (1.0f - p * p - q * q) / d;
  }
}

// accum layout: accum[(b*NQP + q)*NCH + ch]
//   ch 0..63 : sum w*fea_c   64..66 : sum w*fea_{61..63}^2
//   ch 67..69 : sum w*n_{x,y,z}     70 : sum w

__global__ __launch_bounds__(256) void partial_kernel(
    const float* __restrict__ fea,
    const float* __restrict__ nrm,
    const float* __restrict__ msk,
    const float* __restrict__ lqn,
    float* __restrict__ accum)
{
  // B-tile rows: 0..63 fea, 64..66 fea^2(61..63), 67..69 nrm, 70 ones, 71..79 zero
  __shared__ __align__(16) unsigned short v_s[2][80][72];  // 23040 B
  __shared__ __align__(16) float nrm4_s[2][64][4];         // permuted (Cc*n, bias)

  // decode with XCD grouping: all 13 qt-blocks of a (b,ks) slice share blockIdx%8
  const int bx  = blockIdx.x;         // 0..1663
  const int cls = bx & 7;
  const int r0  = bx >> 3;            // 0..207
  const int qt  = r0 % NQT;
  const int sh  = r0 / NQT;           // 0..15
  const int s   = sh * 8 + cls;       // slice id 0..127
  const int b   = s >> 6;
  const int ks  = s & 63;

  const int t    = threadIdx.x;
  const int wv   = t >> 6;            // wave -> M rows 16wv..16wv+15
  const int l    = t & 63;
  const int lq   = l >> 4;            // k-quad
  const int mrow = l & 15;

  const float Cc = __expf(lqn[0]) * 0.57735026919f;   // s/sqrt(3); w = exp(Cc*(cos-1))

  // per-lane query geometry (A-frag row m = mrow)
  float qx, qy, qz;
  pix2qn(g_qtab.idx[qt * QT + 16 * wv + mrow], qx, qy, qz);

  // one-time const rows 70..79 in both buffers
  if (t < 160) {
    int row = 70 + (t >> 4);
    int p4  = (t & 15) * 4;
    unsigned short c = (row == 70) ? (unsigned short)0x3F80 : (unsigned short)0;
    ushort4 cv; cv.x = c; cv.y = c; cv.z = c; cv.w = c;
    *(ushort4*)&v_s[0][row][p4] = cv;
    *(ushort4*)&v_s[1][row][p4] = cv;
  }

  const size_t base_f = (size_t)b * 64 * HW;
  const size_t base_n = (size_t)b * 3 * HW;
  const size_t base_m = (size_t)b * HW;

  const int chb = t >> 4;             // staging channel base
  const int px4 = (t & 15) * 4;       // staging pixel offset
  const int arr = t >> 6;             // staging role: 0..2 nrm.xyz, 3 mask
  // bank-permuted px index: px' = 32*(px>>5) + 4*(px&7) + ((px>>3)&3)
  const int pxp = 32 * (l >> 5) + 4 * (l & 7) + ((l >> 3) & 3);

  f32x4 acc[5];
  #pragma unroll
  for (int nt = 0; nt < 5; ++nt) acc[nt] = (f32x4)(0.0f);

  float4 pf[4];
  float pn = 0.f, pm = 0.f;

  auto load_chunk = [&](int ck) {     // global -> registers (non-blocking)
    int m0 = ks * SLICE + ck * 64;
    #pragma unroll
    for (int i = 0; i < 4; ++i)
      pf[i] = *(const float4*)(fea + base_f + (size_t)(chb + 16 * i) * HW + (size_t)(m0 + px4));
    if (arr < 3) pn = nrm[base_n + (size_t)arr * HW + (size_t)(m0 + l)];
    else         pm = msk[base_m + (size_t)(m0 + l)];
  };
  auto store_chunk = [&](int buf) {   // registers -> LDS (bf16 + w-gen table)
    #pragma unroll
    for (int i = 0; i < 4; ++i) {
      int ch = chb + 16 * i;
      float4 fv = pf[i];
      *(ushort4*)&v_s[buf][ch][px4] = f2b4(fv);
      if (ch >= 61) {
        float4 sq = make_float4(fv.x * fv.x, fv.y * fv.y, fv.z * fv.z, fv.w * fv.w);
        *(ushort4*)&v_s[buf][ch + 3][px4] = f2b4(sq);
      }
    }
    if (arr < 3) {
      v_s[buf][67 + arr][l] = f2b(pn);        // raw nrm for sum(w*n) columns
      nrm4_s[buf][pxp][arr] = Cc * pn;        // premult for w-gen
    } else {
      // bias: -Cc (the cos-1 shift) + mask fold (exp(-2000+..) == 0.f exactly)
      nrm4_s[buf][pxp][3] = -Cc + (pm > 0.5f ? 0.f : -2000.f);
    }
  };

  load_chunk(0);
  store_chunk(0);
  __syncthreads();

  for (int ck = 0; ck < NCHUNK; ++ck) {
    const int buf = ck & 1;
    if (ck + 1 < NCHUNK) load_chunk(ck + 1);   // overlap w/ compute below

    #pragma unroll
    for (int kk = 0; kk < 64; kk += 32) {
      float e[8];
      #pragma unroll
      for (int j = 0; j < 8; ++j) {
        // px = kk + 8*lq + j  ->  permuted row kk + 4*j + lq (conflict-free b128)
        const float4 nv = *(const float4*)&nrm4_s[buf][kk + 4 * j + lq][0];
        float tt = fmaf(qx, nv.x, fmaf(qy, nv.y, fmaf(qz, nv.z, nv.w)));
        e[j] = __expf(tt);
      }
      short8 a;
      #pragma unroll
      for (int p = 0; p < 4; ++p) {
        ushort2 pr = f2b2(e[2 * p], e[2 * p + 1]);
        a[2 * p]     = (short)pr.x;
        a[2 * p + 1] = (short)pr.y;
      }
      #pragma unroll
      for (int nt = 0; nt < 5; ++nt) {
        short8 bb = *(const short8*)&v_s[buf][16 * nt + mrow][kk + 8 * lq];
        acc[nt] = __builtin_amdgcn_mfma_f32_16x16x32_bf16(a, bb, acc[nt], 0, 0, 0);
      }
    }

    if (ck + 1 < NCHUNK) {
      store_chunk(buf ^ 1);
      __syncthreads();                 // single barrier per chunk
    }
  }

  // ---- epilogue: C layout col=lane&15(=n), row=lq*4+reg(=m) -> atomic accumulate ----
  const size_t abase = ((size_t)b * NQP + (size_t)(qt * QT)) * NCH;
  #pragma unroll
  for (int nt = 0; nt < 4; ++nt) {
    #pragma unroll
    for (int rr = 0; rr < 4; ++rr) {
      int qloc = 16 * wv + 4 * lq + rr;
      atomicAdd(&accum[abase + (size_t)qloc * NCH + (size_t)(16 * nt + mrow)], acc[nt][rr]);
    }
  }
  if (mrow < 7) {                      // tile 4: ch 64..70 (sq, wn, sumw)
    #pragma unroll
    for (int rr = 0; rr < 4; ++rr) {
      int qloc = 16 * wv + 4 * lq + rr;
      atomicAdd(&accum[abase + (size_t)qloc * NCH + (size_t)(64 + mrow)], acc[4][rr]);
    }
  }
}

// normalize + scatter: one block per (b, q-tile of 64); out pre-zeroed by memset
__global__ __launch_bounds__(256) void normalize_kernel(
    const float* __restrict__ accum,
    float* __restrict__ out)
{
  __shared__ float a_s[64][NCH];      // 18.4 KB

  const int blk = blockIdx.x;         // 0..25
  const int qt  = blk % NQT;
  const int b   = blk / NQT;
  const int t   = threadIdx.x;

  const float* src = accum + ((size_t)b * NQP + (size_t)(qt * QT)) * NCH;
  for (int i = t; i < 64 * NCH; i += 256) ((float*)a_s)[i] = src[i];
  __syncthreads();

  const int q   = t & 63;             // local query
  const int grp = t >> 6;             // output-channel group
  const int pix = g_qtab.idx[qt * QT + q];
  if (pix < 0) return;                // pad query (wave-uniform per qt=12 tail)

  const float* A = a_s[q];
  const float inv = 1.0f / (A[70] + 1e-9f);
  float gx, gy, gz;
  pix2qn(pix, gx, gy, gz);
  float* ob = out + (size_t)b * 69 * 4096 + pix;

  if (grp == 0) {
    float rm = (gx * A[67] + gy * A[68] + gz * A[69]) * inv;
    float var = 0.f;
    #pragma unroll
    for (int i = 0; i < 3; ++i) {
      float m  = A[61 + i] * inv;
      float sq = A[64 + i] * inv;
      var += sq - m * m;
    }
    ob[0 * 4096] = rm;
    ob[1 * 4096] = var;
    ob[2 * 4096] = gx;
    ob[3 * 4096] = gy;
    ob[4 * 4096] = gz;
    #pragma unroll
    for (int c = 0; c < 13; ++c) ob[(size_t)(5 + c) * 4096] = A[c] * inv;
  } else {
    int c0 = 13 + (grp - 1) * 17;     // 13..29, 30..46, 47..63
    #pragma unroll
    for (int c = 0; c < 17; ++c) ob[(size_t)(5 + c0 + c) * 4096] = A[c0 + c] * inv;
  }
}

extern "C" void kernel_launch(void* const* d_in, const int* in_sizes, int n_in,
                              void* d_out, int out_size, void* d_ws, size_t ws_size,
                              hipStream_t stream) {
  const float* fea = (const float*)d_in[0];
  const float* nrm = (const float*)d_in[1];
  const float* msk = (const float*)d_in[2];
  const float* lqn = (const float*)d_in[3];
  float* accum = (float*)d_ws;        // 2*832*72*4 = 479 KB, zeroed every launch
  float* out   = (float*)d_out;

  hipMemsetAsync(accum, 0, (size_t)2 * NQP * NCH * sizeof(float), stream);
  hipMemsetAsync(d_out, 0, (size_t)out_size * sizeof(float), stream);
  partial_kernel<<<dim3(2 * KSC * NQT), 256, 0, stream>>>(fea, nrm, msk, lqn, accum);
  normalize_kernel<<<dim3(2 * NQT), 256, 0, stream>>>(accum, out);
}

// Round 8
// 122.035 us; speedup vs baseline: 1.0619x; 1.0619x over previous
//
#include <hip/hip_runtime.h>
#include <hip/hip_bf16.h>
#include <cstdint>
#include <cstddef>

// ---------------- problem constants ----------------
#define HW 36864            // 192*192
#define QT 64               // queries per tile (M-tile)
#define NCHA 69             // partial channels: 64 fea + 3 sq + swc + sumw

constexpr bool is_valid_px(int v, int u) {
  int a = 2 * u - 63, b = 2 * v - 63;
  return a * a + b * b < 1024;   // integer-exact (==1024 impossible for odd,odd)
}
constexpr int count_valid() {
  int n = 0;
  for (int v = 0; v < 64; ++v)
    for (int u = 0; u < 64; ++u)
      if (is_valid_px(v, u)) ++n;
  return n;
}
constexpr int NV  = count_valid();          // 812
constexpr int NQT = (NV + QT - 1) / QT;     // 13 tiles of 64
constexpr int NQP = NQT * QT;               // 832 padded queries
constexpr int PLANE = 2 * NQP * NCHA;       // f32 elems per ks-plane of partials

struct QTab {
  short idx[NQP];     // rank -> pixel (or -1 pad)
  short rank[4096];   // pixel -> rank (or -1 invalid)
};
constexpr QTab make_qtab() {
  QTab t{};
  int n = 0;
  for (int p = 0; p < 4096; ++p) {
    int v = p >> 6, u = p & 63;
    if (is_valid_px(v, u)) { t.idx[n] = (short)p; t.rank[p] = (short)n; ++n; }
    else t.rank[p] = -1;
  }
  for (int i = n; i < NQP; ++i) t.idx[i] = -1;
  return t;
}
__constant__ QTab g_qtab = make_qtab();

typedef short short8 __attribute__((ext_vector_type(8)));
typedef float f32x4  __attribute__((ext_vector_type(4)));

__device__ __forceinline__ unsigned short f2b(float f) {  // f32 -> bf16 RNE (scalar)
  unsigned int u = __float_as_uint(f);
  u += 0x7FFFu + ((u >> 16) & 1u);
  return (unsigned short)(u >> 16);
}
__device__ __forceinline__ ushort2 f2b2(float a, float b) {  // packed cvt
  __hip_bfloat162 h = __float22bfloat162_rn(make_float2(a, b));
  return *(ushort2*)&h;
}
__device__ __forceinline__ ushort4 f2b4(float4 v) {
  ushort4 r;
  *(ushort2*)&r.x = f2b2(v.x, v.y);
  *(ushort2*)&r.z = f2b2(v.z, v.w);
  return r;
}
__device__ __forceinline__ void pix2qn(int pix, float& x, float& y, float& z) {
  x = 0.f; y = 0.f; z = 0.f;
  if (pix >= 0) {
    int v = pix >> 6, u = pix & 63;
    float p = (float)(2 * u - 63) * (1.0f / 32.0f);
    float q = -(float)(2 * v - 63) * (1.0f / 32.0f);
    float d = 1.0f + p * p + q * q;
    x = 2.0f * p / d; y = 2.0f * q / d; z = (1.0f - p * p - q * q) / d;
  }
}

// partial layout: part[ ks*PLANE + (b*NQP+q)*NCHA + ch ]  (block-contiguous writes)
//   ch 0..63 : sum w*fea_c   64..66 : sum w*fea_{61..63}^2
//   ch 67 : sum w*cos (folded from wn via qn)   68 : sum w

template<int KSC>
__global__ __launch_bounds__(256) void partial_kernel(
    const float* __restrict__ fea,
    const float* __restrict__ nrm,
    const float* __restrict__ msk,
    const float* __restrict__ lqn,
    float* __restrict__ part)
{
  constexpr int SLICE  = HW / KSC;
  constexpr int NCHUNK = SLICE / 64;

  // B-tile rows: 0..63 fea, 64..66 fea^2(61..63), 67..69 nrm(raw), 70 ones, 71..79 zero
  __shared__ __align__(16) unsigned short v_s[2][80][72];  // 23040 B (2-way alias free)
  __shared__ __align__(16) float nrm4_s[2][64][4];         // permuted (Cc*n, bias)
  __shared__ float ex_s[64][9];

  // decode with XCD grouping: all 13 qt-blocks of a (b,ks) slice share blockIdx%8
  const int bx  = blockIdx.x;
  const int cls = bx & 7;
  const int r0  = bx >> 3;
  const int qt  = r0 % NQT;
  const int sh  = r0 / NQT;
  const int s   = sh * 8 + cls;       // slice id 0..2*KSC-1
  const int b   = s / KSC;
  const int ks  = s % KSC;

  const int t    = threadIdx.x;
  const int wv   = t >> 6;            // wave -> M rows 16wv..16wv+15
  const int l    = t & 63;
  const int lq   = l >> 4;            // k-quad
  const int mrow = l & 15;

  const float Cc = __expf(lqn[0]) * 0.57735026919f;   // s/sqrt(3); w = exp(Cc*(cos-1))

  // per-lane query geometry (A-frag row m = mrow)
  float qx, qy, qz;
  pix2qn(g_qtab.idx[qt * QT + 16 * wv + mrow], qx, qy, qz);

  // one-time const rows 70..79 in both buffers
  if (t < 160) {
    int row = 70 + (t >> 4);
    int p4  = (t & 15) * 4;
    unsigned short c = (row == 70) ? (unsigned short)0x3F80 : (unsigned short)0;
    ushort4 cv; cv.x = c; cv.y = c; cv.z = c; cv.w = c;
    *(ushort4*)&v_s[0][row][p4] = cv;
    *(ushort4*)&v_s[1][row][p4] = cv;
  }

  const size_t base_f = (size_t)b * 64 * HW;
  const size_t base_n = (size_t)b * 3 * HW;
  const size_t base_m = (size_t)b * HW;

  const int chb = t >> 4;             // staging channel base
  const int px4 = (t & 15) * 4;       // staging pixel offset
  const int arr = t >> 6;             // staging role: 0..2 nrm.xyz, 3 mask
  // bank-permuted px index: px' = 32*(px>>5) + 4*(px&7) + ((px>>3)&3)
  const int pxp = 32 * (l >> 5) + 4 * (l & 7) + ((l >> 3) & 3);

  f32x4 acc[5];
  #pragma unroll
  for (int nt = 0; nt < 5; ++nt) acc[nt] = (f32x4)(0.0f);

  float4 pf[4];
  float pn = 0.f, pm = 0.f;

  auto load_chunk = [&](int ck) {     // global -> registers (non-blocking)
    int m0 = ks * SLICE + ck * 64;
    #pragma unroll
    for (int i = 0; i < 4; ++i)
      pf[i] = *(const float4*)(fea + base_f + (size_t)(chb + 16 * i) * HW + (size_t)(m0 + px4));
    if (arr < 3) pn = nrm[base_n + (size_t)arr * HW + (size_t)(m0 + l)];
    else         pm = msk[base_m + (size_t)(m0 + l)];
  };
  auto store_chunk = [&](int buf) {   // registers -> LDS (bf16 + w-gen table)
    #pragma unroll
    for (int i = 0; i < 4; ++i) {
      int ch = chb + 16 * i;
      float4 fv = pf[i];
      *(ushort4*)&v_s[buf][ch][px4] = f2b4(fv);
      if (ch >= 61) {
        float4 sq = make_float4(fv.x * fv.x, fv.y * fv.y, fv.z * fv.z, fv.w * fv.w);
        *(ushort4*)&v_s[buf][ch + 3][px4] = f2b4(sq);
      }
    }
    if (arr < 3) {
      v_s[buf][67 + arr][l] = f2b(pn);        // raw nrm for sum(w*n) columns
      nrm4_s[buf][pxp][arr] = Cc * pn;        // premult for w-gen
    } else {
      // bias: -Cc (the cos-1 shift) + mask fold (exp(-2000+..) == 0.f exactly)
      nrm4_s[buf][pxp][3] = -Cc + (pm > 0.5f ? 0.f : -2000.f);
    }
  };

  load_chunk(0);
  store_chunk(0);
  __syncthreads();

  for (int ck = 0; ck < NCHUNK; ++ck) {
    const int buf = ck & 1;
    if (ck + 1 < NCHUNK) load_chunk(ck + 1);   // overlap w/ compute below

    #pragma unroll
    for (int kk = 0; kk < 64; kk += 32) {
      float e[8];
      #pragma unroll
      for (int j = 0; j < 8; ++j) {
        // px = kk + 8*lq + j  ->  permuted row kk + 4*j + lq (conflict-free b128)
        const float4 nv = *(const float4*)&nrm4_s[buf][kk + 4 * j + lq][0];
        float tt = fmaf(qx, nv.x, fmaf(qy, nv.y, fmaf(qz, nv.z, nv.w)));
        e[j] = __expf(tt);
      }
      short8 a;
      #pragma unroll
      for (int p = 0; p < 4; ++p) {
        ushort2 pr = f2b2(e[2 * p], e[2 * p + 1]);
        a[2 * p]     = (short)pr.x;
        a[2 * p + 1] = (short)pr.y;
      }
      #pragma unroll
      for (int nt = 0; nt < 5; ++nt) {
        short8 bb = *(const short8*)&v_s[buf][16 * nt + mrow][kk + 8 * lq];
        acc[nt] = __builtin_amdgcn_mfma_f32_16x16x32_bf16(a, bb, acc[nt], 0, 0, 0);
      }
    }

    if (ck + 1 < NCHUNK) {
      store_chunk(buf ^ 1);
      __syncthreads();                 // single barrier per chunk
    }
  }

  // ---- epilogue: C layout col=lane&15, row=lq*4+reg ----
  const size_t pbase = (size_t)ks * PLANE + ((size_t)b * NQP + (size_t)(qt * QT)) * NCHA;
  #pragma unroll
  for (int nt = 0; nt < 4; ++nt) {
    #pragma unroll
    for (int rr = 0; rr < 4; ++rr) {
      int qloc = 16 * wv + 4 * lq + rr;
      part[pbase + (size_t)qloc * NCHA + (size_t)(16 * nt + mrow)] = acc[nt][rr];
    }
  }
  if (mrow < 7) {
    #pragma unroll
    for (int rr = 0; rr < 4; ++rr)
      ex_s[16 * wv + 4 * lq + rr][mrow] = acc[4][rr];
  }
  __syncthreads();
  if (t < 64) {
    float gx, gy, gz;
    pix2qn(g_qtab.idx[qt * QT + t], gx, gy, gz);
    float swc = gx * ex_s[t][3] + gy * ex_s[t][4] + gz * ex_s[t][5];
    size_t o = pbase + (size_t)t * NCHA;
    part[o + 64] = ex_s[t][0];
    part[o + 65] = ex_s[t][1];
    part[o + 66] = ex_s[t][2];
    part[o + 67] = swc;
    part[o + 68] = ex_s[t][6];
  }
}

// single tail dispatch: blocks 0..103 reduce+normalize+scatter (16 queries each);
// blocks 104..255 zero-fill invalid-pixel output slots. No memsets needed.
#define NFIN (2 * NQT * 4)            // 104 finalize blocks
#define NTAIL 256                     // total blocks

__global__ __launch_bounds__(256) void finalize_kernel(
    const float* __restrict__ part,
    float* __restrict__ out,
    int ksc)
{
  const int blk = blockIdx.x;
  const int t   = threadIdx.x;

  if (blk < NFIN) {
    __shared__ float sm[16][NCHA];    // 4.4 KB
    const int b   = blk / (NQT * 4);
    const int rem = blk % (NQT * 4);
    const int qt  = rem >> 2;
    const int qr  = rem & 3;          // quarter: queries qt*64 + qr*16 ..+15
    const int q0  = qt * QT + qr * 16;

    const size_t colbase = ((size_t)b * NQP + (size_t)q0) * NCHA;
    for (int i = t; i < 16 * NCHA; i += 256) {     // 1104 sums, coalesced bursts
      float sv = 0.f;
      const size_t off = colbase + (size_t)i;
      #pragma unroll 8
      for (int k = 0; k < ksc; ++k) sv += part[(size_t)k * PLANE + off];
      sm[0][i] = sv;
    }
    __syncthreads();

    for (int i = t; i < 16 * NCHA; i += 256) {
      const int ql = i / NCHA;        // 0..15
      const int oc = i % NCHA;        // output channel
      const int pix = g_qtab.idx[q0 + ql];
      if (pix < 0) continue;
      const float* A = sm[ql];
      const float inv = 1.0f / (A[68] + 1e-9f);
      float gx, gy, gz;
      pix2qn(pix, gx, gy, gz);
      float val;
      if (oc == 0)      val = A[67] * inv;               // rm_cos
      else if (oc == 1) {                                // var
        val = 0.f;
        #pragma unroll
        for (int j = 0; j < 3; ++j) {
          float m  = A[61 + j] * inv;
          float sq = A[64 + j] * inv;
          val += sq - m * m;
        }
      }
      else if (oc == 2) val = gx;
      else if (oc == 3) val = gy;
      else if (oc == 4) val = gz;
      else              val = A[oc - 5] * inv;           // mapped features
      out[((size_t)b * NCHA + (size_t)oc) * 4096 + pix] = val;
    }
  } else {
    // zero-fill: all invalid-pixel slots across both batches (disjoint writes)
    const int start = (blk - NFIN) * 256 + t;
    const int strd  = (NTAIL - NFIN) * 256;
    const int TOT   = 2 * NCHA * 4096;
    for (int i = start; i < TOT; i += strd) {
      if (g_qtab.rank[i & 4095] < 0) out[i] = 0.0f;
    }
  }
}

extern "C" void kernel_launch(void* const* d_in, const int* in_sizes, int n_in,
                              void* d_out, int out_size, void* d_ws, size_t ws_size,
                              hipStream_t stream) {
  const float* fea = (const float*)d_in[0];
  const float* nrm = (const float*)d_in[1];
  const float* msk = (const float*)d_in[2];
  const float* lqn = (const float*)d_in[3];
  float* part = (float*)d_ws;
  float* out  = (float*)d_out;

  const size_t need32 = (size_t)PLANE * 32 * sizeof(float);   // 14.70 MB
  if (ws_size >= need32) {
    partial_kernel<32><<<dim3(2 * 32 * NQT), 256, 0, stream>>>(fea, nrm, msk, lqn, part);
    finalize_kernel<<<dim3(NTAIL), 256, 0, stream>>>(part, out, 32);
  } else {                                                    // 7.35 MB fallback
    partial_kernel<16><<<dim3(2 * 16 * NQT), 256, 0, stream>>>(fea, nrm, msk, lqn, part);
    finalize_kernel<<<dim3(NTAIL), 256, 0, stream>>>(part, out, 16);
  }
}

// Round 9
// 121.221 us; speedup vs baseline: 1.0690x; 1.0067x over previous
//
#include <hip/hip_runtime.h>
#include <hip/hip_bf16.h>
#include <cstdint>
#include <cstddef>

// ---------------- problem constants ----------------
#define HW 36864            // 192*192
#define QT 64               // queries per block (M-tile)
#define NCHA 69             // partial channels: 64 fea + 3 sq + swc + sumw

constexpr bool is_valid_px(int v, int u) {
  int a = 2 * u - 63, b = 2 * v - 63;
  return a * a + b * b < 1024;   // integer-exact (==1024 impossible for odd,odd)
}
constexpr int count_valid() {
  int n = 0;
  for (int v = 0; v < 64; ++v)
    for (int u = 0; u < 64; ++u)
      if (is_valid_px(v, u)) ++n;
  return n;
}
constexpr int NV  = count_valid();          // 812
constexpr int NQT = (NV + QT - 1) / QT;     // 13 tiles of 64
constexpr int NQP = NQT * QT;               // 832 padded queries
constexpr int PLANE = 2 * NQP * NCHA;       // f32 elems per ks-plane of partials

struct QTab {
  short idx[NQP];     // rank -> pixel (or -1 pad)
  short rank[4096];   // pixel -> rank (or -1 invalid)
};
constexpr QTab make_qtab() {
  QTab t{};
  int n = 0;
  for (int p = 0; p < 4096; ++p) {
    int v = p >> 6, u = p & 63;
    if (is_valid_px(v, u)) { t.idx[n] = (short)p; t.rank[p] = (short)n; ++n; }
    else t.rank[p] = -1;
  }
  for (int i = n; i < NQP; ++i) t.idx[i] = -1;
  return t;
}
__constant__ QTab g_qtab = make_qtab();

typedef short short8 __attribute__((ext_vector_type(8)));
typedef float f32x4  __attribute__((ext_vector_type(4)));

__device__ __forceinline__ unsigned short f2b(float f) {  // f32 -> bf16 RNE (scalar)
  unsigned int u = __float_as_uint(f);
  u += 0x7FFFu + ((u >> 16) & 1u);
  return (unsigned short)(u >> 16);
}
__device__ __forceinline__ ushort2 f2b2(float a, float b) {  // packed cvt
  __hip_bfloat162 h = __float22bfloat162_rn(make_float2(a, b));
  return *(ushort2*)&h;
}
__device__ __forceinline__ ushort4 f2b4(float4 v) {
  ushort4 r;
  *(ushort2*)&r.x = f2b2(v.x, v.y);
  *(ushort2*)&r.z = f2b2(v.z, v.w);
  return r;
}
__device__ __forceinline__ void pix2qn(int pix, float& x, float& y, float& z) {
  x = 0.f; y = 0.f; z = 0.f;
  if (pix >= 0) {
    int v = pix >> 6, u = pix & 63;
    float p = (float)(2 * u - 63) * (1.0f / 32.0f);
    float q = -(float)(2 * v - 63) * (1.0f / 32.0f);
    float d = 1.0f + p * p + q * q;
    x = 2.0f * p / d; y = 2.0f * q / d; z = (1.0f - p * p - q * q) / d;
  }
}

// partial layout: part[ ks*PLANE + (b*NQP+q)*NCHA + ch ]  (block-contiguous writes)
//   ch 0..63 : sum w*fea_c   64..66 : sum w*fea_{61..63}^2
//   ch 67 : sum w*cos (folded from wn via qn)   68 : sum w

// 128 threads = 2 waves; each wave owns M=32 queries (2 A-frags) so the nv-table
// and B-fragment LDS reads are shared 2x instead of 4x (LDS pipe was the bottleneck).
template<int KSC>
__global__ __launch_bounds__(128, 2) void partial_kernel(
    const float* __restrict__ fea,
    const float* __restrict__ nrm,
    const float* __restrict__ msk,
    const float* __restrict__ lqn,
    float* __restrict__ part)
{
  constexpr int SLICE  = HW / KSC;
  constexpr int NCHUNK = SLICE / 64;

  // B-tile rows: 0..63 fea, 64..66 fea^2(61..63), 67..69 nrm(raw), 70 ones, 71..79 zero
  __shared__ __align__(16) unsigned short v_s[2][80][72];  // 23040 B (2-way alias free)
  __shared__ __align__(16) float nrm4_s[2][64][4];         // permuted (Cc*n, bias)
  __shared__ float ex_s[64][9];

  // decode with XCD grouping: all 13 qt-blocks of a (b,ks) slice share blockIdx%8
  const int bx  = blockIdx.x;
  const int cls = bx & 7;
  const int r0  = bx >> 3;
  const int qt  = r0 % NQT;
  const int sh  = r0 / NQT;
  const int s   = sh * 8 + cls;       // slice id 0..2*KSC-1
  const int b   = s / KSC;
  const int ks  = s % KSC;

  const int t    = threadIdx.x;       // 0..127
  const int wv   = t >> 6;            // wave 0/1 -> M rows 32wv..32wv+31
  const int l    = t & 63;
  const int lq   = l >> 4;            // k-quad
  const int mrow = l & 15;

  const float Cc = __expf(lqn[0]) * 0.57735026919f;   // s/sqrt(3); w = exp(Cc*(cos-1))

  // per-lane query geometry for the wave's two 16-row strips
  float qx[2], qy[2], qz[2];
  pix2qn(g_qtab.idx[qt * QT + 32 * wv + mrow],      qx[0], qy[0], qz[0]);
  pix2qn(g_qtab.idx[qt * QT + 32 * wv + 16 + mrow], qx[1], qy[1], qz[1]);

  // one-time const rows 70..79 in both buffers (160 ushort4 slots, 128 threads)
  for (int s0 = t; s0 < 160; s0 += 128) {
    int row = 70 + (s0 >> 4);
    int p4  = (s0 & 15) * 4;
    unsigned short c = (row == 70) ? (unsigned short)0x3F80 : (unsigned short)0;
    ushort4 cv; cv.x = c; cv.y = c; cv.z = c; cv.w = c;
    *(ushort4*)&v_s[0][row][p4] = cv;
    *(ushort4*)&v_s[1][row][p4] = cv;
  }

  const size_t base_f = (size_t)b * 64 * HW;
  const size_t base_n = (size_t)b * 3 * HW;
  const size_t base_m = (size_t)b * HW;

  const int chb = t >> 4;             // staging channel base 0..7 (ch = chb + 8*i)
  const int px4 = (t & 15) * 4;       // staging pixel offset
  // bank-permuted px index: px' = 32*(px>>5) + 4*(px&7) + ((px>>3)&3)
  const int pxp = 32 * (l >> 5) + 4 * (l & 7) + ((l >> 3) & 3);

  f32x4 acc[2][5];
  #pragma unroll
  for (int h = 0; h < 2; ++h)
    #pragma unroll
    for (int nt = 0; nt < 5; ++nt) acc[h][nt] = (f32x4)(0.0f);

  float4 pf[8];
  float pnA = 0.f, pnB = 0.f;

  auto load_chunk = [&](int ck) {     // global -> registers (non-blocking)
    int m0 = ks * SLICE + ck * 64;
    #pragma unroll
    for (int i = 0; i < 8; ++i)
      pf[i] = *(const float4*)(fea + base_f + (size_t)(chb + 8 * i) * HW + (size_t)(m0 + px4));
    // roles: wave0 -> nrm.x + nrm.z ; wave1 -> nrm.y + mask
    pnA = nrm[base_n + (size_t)wv * HW + (size_t)(m0 + l)];
    pnB = (wv == 0) ? nrm[base_n + (size_t)2 * HW + (size_t)(m0 + l)]
                    : msk[base_m + (size_t)(m0 + l)];
  };
  auto store_chunk = [&](int buf) {   // registers -> LDS (bf16 + w-gen table)
    #pragma unroll
    for (int i = 0; i < 8; ++i) {
      int ch = chb + 8 * i;
      float4 fv = pf[i];
      *(ushort4*)&v_s[buf][ch][px4] = f2b4(fv);
      if (ch >= 61) {
        float4 sq = make_float4(fv.x * fv.x, fv.y * fv.y, fv.z * fv.z, fv.w * fv.w);
        *(ushort4*)&v_s[buf][ch + 3][px4] = f2b4(sq);
      }
    }
    v_s[buf][67 + wv][l] = f2b(pnA);          // raw nrm.x / nrm.y
    nrm4_s[buf][pxp][wv] = Cc * pnA;
    if (wv == 0) {
      v_s[buf][69][l] = f2b(pnB);             // raw nrm.z
      nrm4_s[buf][pxp][2] = Cc * pnB;
    } else {
      // bias: -Cc (the cos-1 shift) + mask fold (exp(-2000+..) == 0.f exactly)
      nrm4_s[buf][pxp][3] = -Cc + (pnB > 0.5f ? 0.f : -2000.f);
    }
  };

  load_chunk(0);
  store_chunk(0);
  __syncthreads();

  for (int ck = 0; ck < NCHUNK; ++ck) {
    const int buf = ck & 1;
    if (ck + 1 < NCHUNK) load_chunk(ck + 1);   // overlap w/ compute below

    #pragma unroll
    for (int kk = 0; kk < 64; kk += 32) {
      float e0[8], e1[8];
      #pragma unroll
      for (int j = 0; j < 8; ++j) {
        // px = kk + 8*lq + j  ->  permuted row kk + 4*j + lq (conflict-free b128)
        const float4 nv = *(const float4*)&nrm4_s[buf][kk + 4 * j + lq][0];
        float t0 = fmaf(qx[0], nv.x, fmaf(qy[0], nv.y, fmaf(qz[0], nv.z, nv.w)));
        float t1 = fmaf(qx[1], nv.x, fmaf(qy[1], nv.y, fmaf(qz[1], nv.z, nv.w)));
        e0[j] = __expf(t0);
        e1[j] = __expf(t1);
      }
      short8 a0, a1;
      #pragma unroll
      for (int p = 0; p < 4; ++p) {
        ushort2 p0 = f2b2(e0[2 * p], e0[2 * p + 1]);
        ushort2 p1 = f2b2(e1[2 * p], e1[2 * p + 1]);
        a0[2 * p] = (short)p0.x; a0[2 * p + 1] = (short)p0.y;
        a1[2 * p] = (short)p1.x; a1[2 * p + 1] = (short)p1.y;
      }
      #pragma unroll
      for (int nt = 0; nt < 5; ++nt) {
        short8 bb = *(const short8*)&v_s[buf][16 * nt + mrow][kk + 8 * lq];
        acc[0][nt] = __builtin_amdgcn_mfma_f32_16x16x32_bf16(a0, bb, acc[0][nt], 0, 0, 0);
        acc[1][nt] = __builtin_amdgcn_mfma_f32_16x16x32_bf16(a1, bb, acc[1][nt], 0, 0, 0);
      }
    }

    if (ck + 1 < NCHUNK) {
      store_chunk(buf ^ 1);
      __syncthreads();                 // single barrier per chunk
    }
  }

  // ---- epilogue: C layout col=lane&15, row=lq*4+reg ----
  const size_t pbase = (size_t)ks * PLANE + ((size_t)b * NQP + (size_t)(qt * QT)) * NCHA;
  #pragma unroll
  for (int h = 0; h < 2; ++h) {
    #pragma unroll
    for (int nt = 0; nt < 4; ++nt) {
      #pragma unroll
      for (int rr = 0; rr < 4; ++rr) {
        int qloc = 32 * wv + 16 * h + 4 * lq + rr;
        part[pbase + (size_t)qloc * NCHA + (size_t)(16 * nt + mrow)] = acc[h][nt][rr];
      }
    }
    if (mrow < 7) {
      #pragma unroll
      for (int rr = 0; rr < 4; ++rr)
        ex_s[32 * wv + 16 * h + 4 * lq + rr][mrow] = acc[h][4][rr];
    }
  }
  __syncthreads();
  if (t < 64) {
    float gx, gy, gz;
    pix2qn(g_qtab.idx[qt * QT + t], gx, gy, gz);
    float swc = gx * ex_s[t][3] + gy * ex_s[t][4] + gz * ex_s[t][5];
    size_t o = pbase + (size_t)t * NCHA;
    part[o + 64] = ex_s[t][0];
    part[o + 65] = ex_s[t][1];
    part[o + 66] = ex_s[t][2];
    part[o + 67] = swc;
    part[o + 68] = ex_s[t][6];
  }
}

// single tail dispatch: blocks 0..207 reduce+normalize+scatter (8 queries each);
// blocks 208..415 zero-fill invalid-pixel output slots. No memsets needed.
#define NFIN (2 * NQT * 8)            // 208 finalize blocks
#define NTAIL (2 * NFIN)              // 416 total blocks

__global__ __launch_bounds__(256) void finalize_kernel(
    const float* __restrict__ part,
    float* __restrict__ out,
    int ksc)
{
  const int blk = blockIdx.x;
  const int t   = threadIdx.x;

  if (blk < NFIN) {
    __shared__ float sm[8][NCHA];     // 2.2 KB
    const int b   = blk / (NQT * 8);
    const int rem = blk % (NQT * 8);
    const int qt  = rem >> 3;
    const int qr  = rem & 7;          // eighth: queries qt*64 + qr*8 ..+7
    const int q0  = qt * QT + qr * 8;

    const size_t colbase = ((size_t)b * NQP + (size_t)q0) * NCHA;
    for (int i = t; i < 8 * NCHA; i += 256) {      // 552 sums, coalesced bursts
      float sv = 0.f;
      const size_t off = colbase + (size_t)i;
      #pragma unroll 8
      for (int k = 0; k < ksc; ++k) sv += part[(size_t)k * PLANE + off];
      sm[0][i] = sv;
    }
    __syncthreads();

    for (int i = t; i < 8 * NCHA; i += 256) {
      const int ql = i / NCHA;        // 0..7
      const int oc = i % NCHA;        // output channel
      const int pix = g_qtab.idx[q0 + ql];
      if (pix < 0) continue;
      const float* A = sm[ql];
      const float inv = 1.0f / (A[68] + 1e-9f);
      float gx, gy, gz;
      pix2qn(pix, gx, gy, gz);
      float val;
      if (oc == 0)      val = A[67] * inv;               // rm_cos
      else if (oc == 1) {                                // var
        val = 0.f;
        #pragma unroll
        for (int j = 0; j < 3; ++j) {
          float m  = A[61 + j] * inv;
          float sq = A[64 + j] * inv;
          val += sq - m * m;
        }
      }
      else if (oc == 2) val = gx;
      else if (oc == 3) val = gy;
      else if (oc == 4) val = gz;
      else              val = A[oc - 5] * inv;           // mapped features
      out[((size_t)b * NCHA + (size_t)oc) * 4096 + pix] = val;
    }
  } else {
    // zero-fill: all invalid-pixel slots across both batches (disjoint writes)
    const int start = (blk - NFIN) * 256 + t;
    const int strd  = (NTAIL - NFIN) * 256;
    const int TOT   = 2 * NCHA * 4096;
    for (int i = start; i < TOT; i += strd) {
      if (g_qtab.rank[i & 4095] < 0) out[i] = 0.0f;
    }
  }
}

extern "C" void kernel_launch(void* const* d_in, const int* in_sizes, int n_in,
                              void* d_out, int out_size, void* d_ws, size_t ws_size,
                              hipStream_t stream) {
  const float* fea = (const float*)d_in[0];
  const float* nrm = (const float*)d_in[1];
  const float* msk = (const float*)d_in[2];
  const float* lqn = (const float*)d_in[3];
  float* part = (float*)d_ws;
  float* out  = (float*)d_out;

  const size_t need32 = (size_t)PLANE * 32 * sizeof(float);   // 14.70 MB
  if (ws_size >= need32) {
    partial_kernel<32><<<dim3(2 * 32 * NQT), 128, 0, stream>>>(fea, nrm, msk, lqn, part);
    finalize_kernel<<<dim3(NTAIL), 256, 0, stream>>>(part, out, 32);
  } else {                                                    // 7.35 MB fallback
    partial_kernel<16><<<dim3(2 * 16 * NQT), 128, 0, stream>>>(fea, nrm, msk, lqn, part);
    finalize_kernel<<<dim3(NTAIL), 256, 0, stream>>>(part, out, 16);
  }
}

// Round 10
// 118.886 us; speedup vs baseline: 1.0900x; 1.0196x over previous
//
#include <hip/hip_runtime.h>
#include <hip/hip_bf16.h>
#include <cstdint>
#include <cstddef>

// ---------------- problem constants ----------------
#define HW 36864            // 192*192
#define QT 64               // queries per block (M-tile)
#define NCHA 69             // partial channels: 64 fea + 3 sq + swc + sumw

constexpr bool is_valid_px(int v, int u) {
  int a = 2 * u - 63, b = 2 * v - 63;
  return a * a + b * b < 1024;   // integer-exact (==1024 impossible for odd,odd)
}
constexpr int count_valid() {
  int n = 0;
  for (int v = 0; v < 64; ++v)
    for (int u = 0; u < 64; ++u)
      if (is_valid_px(v, u)) ++n;
  return n;
}
constexpr int NV  = count_valid();          // 812
constexpr int NQT = (NV + QT - 1) / QT;     // 13 tiles of 64
constexpr int NQP = NQT * QT;               // 832 padded queries
constexpr int PLANE = 2 * NQP * NCHA;       // f32 elems per ks-plane of partials

struct QTab {
  short idx[NQP];     // rank -> pixel (or -1 pad)
  short rank[4096];   // pixel -> rank (or -1 invalid)
};
constexpr QTab make_qtab() {
  QTab t{};
  int n = 0;
  for (int p = 0; p < 4096; ++p) {
    int v = p >> 6, u = p & 63;
    if (is_valid_px(v, u)) { t.idx[n] = (short)p; t.rank[p] = (short)n; ++n; }
    else t.rank[p] = -1;
  }
  for (int i = n; i < NQP; ++i) t.idx[i] = -1;
  return t;
}
__constant__ QTab g_qtab = make_qtab();

typedef short short8 __attribute__((ext_vector_type(8)));
typedef float f32x4  __attribute__((ext_vector_type(4)));

__device__ __forceinline__ unsigned short f2b(float f) {  // f32 -> bf16 RNE (scalar)
  unsigned int u = __float_as_uint(f);
  u += 0x7FFFu + ((u >> 16) & 1u);
  return (unsigned short)(u >> 16);
}
__device__ __forceinline__ ushort2 f2b2(float a, float b) {  // packed cvt
  __hip_bfloat162 h = __float22bfloat162_rn(make_float2(a, b));
  return *(ushort2*)&h;
}
__device__ __forceinline__ ushort4 f2b4(float4 v) {
  ushort4 r;
  *(ushort2*)&r.x = f2b2(v.x, v.y);
  *(ushort2*)&r.z = f2b2(v.z, v.w);
  return r;
}
__device__ __forceinline__ void pix2qn(int pix, float& x, float& y, float& z) {
  x = 0.f; y = 0.f; z = 0.f;
  if (pix >= 0) {
    int v = pix >> 6, u = pix & 63;
    float p = (float)(2 * u - 63) * (1.0f / 32.0f);
    float q = -(float)(2 * v - 63) * (1.0f / 32.0f);
    float d = 1.0f + p * p + q * q;
    x = 2.0f * p / d; y = 2.0f * q / d; z = (1.0f - p * p - q * q) / d;
  }
}

// partial layout: part[ ks*PLANE + (b*NQP+q)*NCHA + ch ]  (block-contiguous writes)
//   ch 0..63 : sum w*fea_c   64..66 : sum w*fea_{61..63}^2
//   ch 67 : sum w*cos (folded from wn via qn)   68 : sum w

// 256 threads = 4 waves; wave w owns (M-half = w&1, K-half = (w>>1)*32): each wave
// reads one nv stream + one B-frag stream for TWO A-fragments (M=32) -> R9's LDS
// traffic at R8's wave count. K-halves merged once at the end via LDS (aliased
// onto the dead v_s double-buffer; ex_s aliased too -> block LDS 25 KB).
template<int KSC>
__global__ __launch_bounds__(256, 4) void partial_kernel(
    const float* __restrict__ fea,
    const float* __restrict__ nrm,
    const float* __restrict__ msk,
    const float* __restrict__ lqn,
    float* __restrict__ part)
{
  constexpr int SLICE  = HW / KSC;
  constexpr int NCHUNK = SLICE / 64;

  // B-tile rows: 0..63 fea, 64..66 fea^2(61..63), 67..69 nrm(raw), 70 ones, 71..79 zero
  __shared__ __align__(16) unsigned short v_s[2][80][72];  // 23040 B (2-way alias free)
  __shared__ __align__(16) float nrm4_s[2][64][4];         // permuted (Cc*n, bias)

  // decode with XCD grouping: all 13 qt-blocks of a (b,ks) slice share blockIdx%8
  const int bx  = blockIdx.x;
  const int cls = bx & 7;
  const int r0  = bx >> 3;
  const int qt  = r0 % NQT;
  const int sh  = r0 / NQT;
  const int s   = sh * 8 + cls;       // slice id 0..2*KSC-1
  const int b   = s / KSC;
  const int ks  = s % KSC;

  const int t    = threadIdx.x;       // 0..255
  const int wv   = t >> 6;
  const int Mh   = wv & 1;            // M-half: queries 32*Mh..32*Mh+31
  const int kko  = (wv >> 1) * 32;    // K-half offset 0/32
  const int l    = t & 63;
  const int lq   = l >> 4;            // k-quad
  const int mrow = l & 15;

  const float Cc = __expf(lqn[0]) * 0.57735026919f;   // s/sqrt(3); w = exp(Cc*(cos-1))

  // per-lane query geometry for this wave's two 16-row strips
  float qx[2], qy[2], qz[2];
  pix2qn(g_qtab.idx[qt * QT + 32 * Mh + mrow],      qx[0], qy[0], qz[0]);
  pix2qn(g_qtab.idx[qt * QT + 32 * Mh + 16 + mrow], qx[1], qy[1], qz[1]);

  // one-time const rows 70..79 in both buffers
  if (t < 160) {
    int row = 70 + (t >> 4);
    int p4  = (t & 15) * 4;
    unsigned short c = (row == 70) ? (unsigned short)0x3F80 : (unsigned short)0;
    ushort4 cv; cv.x = c; cv.y = c; cv.z = c; cv.w = c;
    *(ushort4*)&v_s[0][row][p4] = cv;
    *(ushort4*)&v_s[1][row][p4] = cv;
  }

  const size_t base_f = (size_t)b * 64 * HW;
  const size_t base_n = (size_t)b * 3 * HW;
  const size_t base_m = (size_t)b * HW;

  const int chb = t >> 4;             // staging channel base (ch = chb + 16*i)
  const int px4 = (t & 15) * 4;       // staging pixel offset
  const int arr = t >> 6;             // staging role: 0..2 nrm.xyz, 3 mask
  // bank-permuted px index: px' = 32*(px>>5) + 4*(px&7) + ((px>>3)&3)
  const int pxp = 32 * (l >> 5) + 4 * (l & 7) + ((l >> 3) & 3);

  f32x4 acc[2][5];
  #pragma unroll
  for (int h = 0; h < 2; ++h)
    #pragma unroll
    for (int nt = 0; nt < 5; ++nt) acc[h][nt] = (f32x4)(0.0f);

  float4 pf[4];
  float pn = 0.f, pm = 0.f;

  auto load_chunk = [&](int ck) {     // global -> registers (non-blocking)
    int m0 = ks * SLICE + ck * 64;
    #pragma unroll
    for (int i = 0; i < 4; ++i)
      pf[i] = *(const float4*)(fea + base_f + (size_t)(chb + 16 * i) * HW + (size_t)(m0 + px4));
    if (arr < 3) pn = nrm[base_n + (size_t)arr * HW + (size_t)(m0 + l)];
    else         pm = msk[base_m + (size_t)(m0 + l)];
  };
  auto store_chunk = [&](int buf) {   // registers -> LDS (bf16 + w-gen table)
    #pragma unroll
    for (int i = 0; i < 4; ++i) {
      int ch = chb + 16 * i;
      float4 fv = pf[i];
      *(ushort4*)&v_s[buf][ch][px4] = f2b4(fv);
      if (ch >= 61) {
        float4 sq = make_float4(fv.x * fv.x, fv.y * fv.y, fv.z * fv.z, fv.w * fv.w);
        *(ushort4*)&v_s[buf][ch + 3][px4] = f2b4(sq);
      }
    }
    if (arr < 3) {
      v_s[buf][67 + arr][l] = f2b(pn);        // raw nrm for sum(w*n) columns
      nrm4_s[buf][pxp][arr] = Cc * pn;        // premult for w-gen
    } else {
      // bias: -Cc (the cos-1 shift) + mask fold (exp(-2000+..) == 0.f exactly)
      nrm4_s[buf][pxp][3] = -Cc + (pm > 0.5f ? 0.f : -2000.f);
    }
  };

  load_chunk(0);
  store_chunk(0);
  __syncthreads();

  for (int ck = 0; ck < NCHUNK; ++ck) {
    const int buf = ck & 1;
    if (ck + 1 < NCHUNK) load_chunk(ck + 1);   // overlap w/ compute below

    // ---- this wave's single K-half: 8 nv reads, 16 exps, 5 B reads, 10 MFMAs ----
    float e0[8], e1[8];
    #pragma unroll
    for (int j = 0; j < 8; ++j) {
      // px = kko + 8*lq + j  ->  permuted row kko + 4*j + lq (conflict-free b128)
      const float4 nv = *(const float4*)&nrm4_s[buf][kko + 4 * j + lq][0];
      float t0 = fmaf(qx[0], nv.x, fmaf(qy[0], nv.y, fmaf(qz[0], nv.z, nv.w)));
      float t1 = fmaf(qx[1], nv.x, fmaf(qy[1], nv.y, fmaf(qz[1], nv.z, nv.w)));
      e0[j] = __expf(t0);
      e1[j] = __expf(t1);
    }
    short8 a0, a1;
    #pragma unroll
    for (int p = 0; p < 4; ++p) {
      ushort2 p0 = f2b2(e0[2 * p], e0[2 * p + 1]);
      ushort2 p1 = f2b2(e1[2 * p], e1[2 * p + 1]);
      a0[2 * p] = (short)p0.x; a0[2 * p + 1] = (short)p0.y;
      a1[2 * p] = (short)p1.x; a1[2 * p + 1] = (short)p1.y;
    }
    #pragma unroll
    for (int nt = 0; nt < 5; ++nt) {
      short8 bb = *(const short8*)&v_s[buf][16 * nt + mrow][kko + 8 * lq];
      acc[0][nt] = __builtin_amdgcn_mfma_f32_16x16x32_bf16(a0, bb, acc[0][nt], 0, 0, 0);
      acc[1][nt] = __builtin_amdgcn_mfma_f32_16x16x32_bf16(a1, bb, acc[1][nt], 0, 0, 0);
    }

    if (ck + 1 < NCHUNK) {
      store_chunk(buf ^ 1);
      __syncthreads();                 // single barrier per chunk
    }
  }

  // ---- merge K-halves through LDS (alias dead v_s), then epilogue ----
  __syncthreads();                     // all v_s reads done before aliasing
  float* scr = (float*)&v_s[0][0][0];  // [64 q][80 ch] f32 = 20480 B
  float* exs = scr + 64 * 80;          // [64 q][9]     f32 = 2304 B (total 22784 <= 23040)

  if (kko) {                           // waves 2,3: publish their half
    #pragma unroll
    for (int h = 0; h < 2; ++h)
      #pragma unroll
      for (int nt = 0; nt < 5; ++nt)
        #pragma unroll
        for (int rr = 0; rr < 4; ++rr) {
          int qloc = 32 * Mh + 16 * h + 4 * lq + rr;
          scr[qloc * 80 + 16 * nt + mrow] = acc[h][nt][rr];
        }
  }
  __syncthreads();
  const size_t pbase = (size_t)ks * PLANE + ((size_t)b * NQP + (size_t)(qt * QT)) * NCHA;
  if (!kko) {                          // waves 0,1: merge + write partials
    #pragma unroll
    for (int h = 0; h < 2; ++h) {
      #pragma unroll
      for (int nt = 0; nt < 5; ++nt)
        #pragma unroll
        for (int rr = 0; rr < 4; ++rr) {
          int qloc = 32 * Mh + 16 * h + 4 * lq + rr;
          acc[h][nt][rr] += scr[qloc * 80 + 16 * nt + mrow];
        }
      #pragma unroll
      for (int nt = 0; nt < 4; ++nt)
        #pragma unroll
        for (int rr = 0; rr < 4; ++rr) {
          int qloc = 32 * Mh + 16 * h + 4 * lq + rr;
          part[pbase + (size_t)qloc * NCHA + (size_t)(16 * nt + mrow)] = acc[h][nt][rr];
        }
      if (mrow < 7) {
        #pragma unroll
        for (int rr = 0; rr < 4; ++rr)
          exs[(32 * Mh + 16 * h + 4 * lq + rr) * 9 + mrow] = acc[h][4][rr];
      }
    }
  }
  __syncthreads();
  if (t < 64) {
    float gx, gy, gz;
    pix2qn(g_qtab.idx[qt * QT + t], gx, gy, gz);
    const float* E = exs + t * 9;
    float swc = gx * E[3] + gy * E[4] + gz * E[5];
    size_t o = pbase + (size_t)t * NCHA;
    part[o + 64] = E[0];
    part[o + 65] = E[1];
    part[o + 66] = E[2];
    part[o + 67] = swc;
    part[o + 68] = E[6];
  }
}

// single tail dispatch: blocks 0..207 reduce+normalize+scatter (8 queries each);
// blocks 208..415 zero-fill invalid-pixel output slots. No memsets needed.
#define NFIN (2 * NQT * 8)            // 208 finalize blocks
#define NTAIL (2 * NFIN)              // 416 total blocks

__global__ __launch_bounds__(256) void finalize_kernel(
    const float* __restrict__ part,
    float* __restrict__ out,
    int ksc)
{
  const int blk = blockIdx.x;
  const int t   = threadIdx.x;

  if (blk < NFIN) {
    __shared__ float sm[8][NCHA];     // 2.2 KB
    const int b   = blk / (NQT * 8);
    const int rem = blk % (NQT * 8);
    const int qt  = rem >> 3;
    const int qr  = rem & 7;          // eighth: queries qt*64 + qr*8 ..+7
    const int q0  = qt * QT + qr * 8;

    const size_t colbase = ((size_t)b * NQP + (size_t)q0) * NCHA;
    for (int i = t; i < 8 * NCHA; i += 256) {      // 552 sums, coalesced bursts
      float sv = 0.f;
      const size_t off = colbase + (size_t)i;
      #pragma unroll 8
      for (int k = 0; k < ksc; ++k) sv += part[(size_t)k * PLANE + off];
      sm[0][i] = sv;
    }
    __syncthreads();

    for (int i = t; i < 8 * NCHA; i += 256) {
      const int ql = i / NCHA;        // 0..7
      const int oc = i % NCHA;        // output channel
      const int pix = g_qtab.idx[q0 + ql];
      if (pix < 0) continue;
      const float* A = sm[ql];
      const float inv = 1.0f / (A[68] + 1e-9f);
      float gx, gy, gz;
      pix2qn(pix, gx, gy, gz);
      float val;
      if (oc == 0)      val = A[67] * inv;               // rm_cos
      else if (oc == 1) {                                // var
        val = 0.f;
        #pragma unroll
        for (int j = 0; j < 3; ++j) {
          float m  = A[61 + j] * inv;
          float sq = A[64 + j] * inv;
          val += sq - m * m;
        }
      }
      else if (oc == 2) val = gx;
      else if (oc == 3) val = gy;
      else if (oc == 4) val = gz;
      else              val = A[oc - 5] * inv;           // mapped features
      out[((size_t)b * NCHA + (size_t)oc) * 4096 + pix] = val;
    }
  } else {
    // zero-fill: all invalid-pixel slots across both batches (disjoint writes)
    const int start = (blk - NFIN) * 256 + t;
    const int strd  = (NTAIL - NFIN) * 256;
    const int TOT   = 2 * NCHA * 4096;
    for (int i = start; i < TOT; i += strd) {
      if (g_qtab.rank[i & 4095] < 0) out[i] = 0.0f;
    }
  }
}

extern "C" void kernel_launch(void* const* d_in, const int* in_sizes, int n_in,
                              void* d_out, int out_size, void* d_ws, size_t ws_size,
                              hipStream_t stream) {
  const float* fea = (const float*)d_in[0];
  const float* nrm = (const float*)d_in[1];
  const float* msk = (const float*)d_in[2];
  const float* lqn = (const float*)d_in[3];
  float* part = (float*)d_ws;
  float* out  = (float*)d_out;

  const size_t need64 = (size_t)PLANE * 64 * sizeof(float);   // 29.39 MB
  const size_t need32 = (size_t)PLANE * 32 * sizeof(float);   // 14.70 MB
  if (ws_size >= need64) {            // 1664 blocks -> ~6 blocks/CU resident
    partial_kernel<64><<<dim3(2 * 64 * NQT), 256, 0, stream>>>(fea, nrm, msk, lqn, part);
    finalize_kernel<<<dim3(NTAIL), 256, 0, stream>>>(part, out, 64);
  } else if (ws_size >= need32) {     // proven 832-block config
    partial_kernel<32><<<dim3(2 * 32 * NQT), 256, 0, stream>>>(fea, nrm, msk, lqn, part);
    finalize_kernel<<<dim3(NTAIL), 256, 0, stream>>>(part, out, 32);
  } else {                            // 7.35 MB fallback
    partial_kernel<16><<<dim3(2 * 16 * NQT), 256, 0, stream>>>(fea, nrm, msk, lqn, part);
    finalize_kernel<<<dim3(NTAIL), 256, 0, stream>>>(part, out, 16);
  }
}

// Round 11
// 117.344 us; speedup vs baseline: 1.1043x; 1.0131x over previous
//
#include <hip/hip_runtime.h>
#include <hip/hip_bf16.h>
#include <cstdint>
#include <cstddef>

// ---------------- problem constants ----------------
#define HW 36864            // 192*192
#define QT 64               // queries per block (M-tile)
#define NCHA 69             // partial channels: 64 fea + 3 sq + swc + sumw
#define NCHK 576            // HW/64 total 64-px chunks

constexpr bool is_valid_px(int v, int u) {
  int a = 2 * u - 63, b = 2 * v - 63;
  return a * a + b * b < 1024;   // integer-exact (==1024 impossible for odd,odd)
}
constexpr int count_valid() {
  int n = 0;
  for (int v = 0; v < 64; ++v)
    for (int u = 0; u < 64; ++u)
      if (is_valid_px(v, u)) ++n;
  return n;
}
constexpr int NV  = count_valid();          // 812
constexpr int NQT = (NV + QT - 1) / QT;     // 13 tiles of 64
constexpr int NQP = NQT * QT;               // 832 padded queries
constexpr int PLANE = 2 * NQP * NCHA;       // f32 elems per ks-plane of partials

// workspace layout (bytes): [Bm bf16 11.80 MB][nv f32 1.18 MB][part f32 KSC*PLANE*4]
constexpr size_t BM_SHORTS  = (size_t)2 * NCHK * 80 * 64;     // 5,898,240
constexpr size_t BM_BYTES   = BM_SHORTS * 2;                  // 11,796,480
constexpr size_t NV_BYTES   = (size_t)2 * HW * 4 * 4;         // 1,179,648
constexpr size_t PART_OFF   = BM_BYTES + NV_BYTES;            // 12,976,128 (16B aligned)

struct QTab {
  short idx[NQP];     // rank -> pixel (or -1 pad)
  short rank[4096];   // pixel -> rank (or -1 invalid)
};
constexpr QTab make_qtab() {
  QTab t{};
  int n = 0;
  for (int p = 0; p < 4096; ++p) {
    int v = p >> 6, u = p & 63;
    if (is_valid_px(v, u)) { t.idx[n] = (short)p; t.rank[p] = (short)n; ++n; }
    else t.rank[p] = -1;
  }
  for (int i = n; i < NQP; ++i) t.idx[i] = -1;
  return t;
}
__constant__ QTab g_qtab = make_qtab();

typedef short short8 __attribute__((ext_vector_type(8)));
typedef float f32x4  __attribute__((ext_vector_type(4)));

__device__ __forceinline__ unsigned short f2b(float f) {  // f32 -> bf16 RNE (scalar)
  unsigned int u = __float_as_uint(f);
  u += 0x7FFFu + ((u >> 16) & 1u);
  return (unsigned short)(u >> 16);
}
__device__ __forceinline__ ushort2 f2b2(float a, float b) {  // packed cvt
  __hip_bfloat162 h = __float22bfloat162_rn(make_float2(a, b));
  return *(ushort2*)&h;
}
__device__ __forceinline__ void pix2qn(int pix, float& x, float& y, float& z) {
  x = 0.f; y = 0.f; z = 0.f;
  if (pix >= 0) {
    int v = pix >> 6, u = pix & 63;
    float p = (float)(2 * u - 63) * (1.0f / 32.0f);
    float q = -(float)(2 * v - 63) * (1.0f / 32.0f);
    float d = 1.0f + p * p + q * q;
    x = 2.0f * p / d; y = 2.0f * q / d; z = (1.0f - p * p - q * q) / d;
  }
}

// ---------- prep: build bf16 B-matrix + w-gen table ONCE (was re-done 13x) ----------
// Bm rows per chunk: 0..63 fea, 64..66 fea^2(61..63), 67..69 nrm, 70 ones, 71..79 zero
#define PREP_BM_BLKS 2880   // 2*576*80*8 groups / 256
#define PREP_NV_BLKS 288    // 2*36864 px / 256

__global__ __launch_bounds__(256) void prep_kernel(
    const float* __restrict__ fea,
    const float* __restrict__ nrm,
    const float* __restrict__ msk,
    const float* __restrict__ lqn,
    unsigned short* __restrict__ Bm,
    float* __restrict__ nv)
{
  const float Cc = __expf(lqn[0]) * 0.57735026919f;   // s/sqrt(3)
  if (blockIdx.x < PREP_BM_BLKS) {
    int gid = blockIdx.x * 256 + threadIdx.x;          // group id
    int g   = gid & 7;
    int row = (gid >> 3) % 80;
    int chk = ((gid >> 3) / 80) % NCHK;
    int b   = gid / (8 * 80 * NCHK);
    int px0 = chk * 64 + g * 8;
    float v[8];
    if (row < 64) {
      const float* p = fea + ((size_t)b * 64 + row) * HW + px0;
      #pragma unroll
      for (int i = 0; i < 8; ++i) v[i] = p[i];
    } else if (row < 67) {
      const float* p = fea + ((size_t)b * 64 + (61 + row - 64)) * HW + px0;
      #pragma unroll
      for (int i = 0; i < 8; ++i) { float x = p[i]; v[i] = x * x; }
    } else if (row < 70) {
      const float* p = nrm + ((size_t)b * 3 + (row - 67)) * HW + px0;
      #pragma unroll
      for (int i = 0; i < 8; ++i) v[i] = p[i];
    } else {
      float c = (row == 70) ? 1.0f : 0.0f;
      #pragma unroll
      for (int i = 0; i < 8; ++i) v[i] = c;
    }
    short8 o;
    #pragma unroll
    for (int p2 = 0; p2 < 4; ++p2) {
      ushort2 pr = f2b2(v[2 * p2], v[2 * p2 + 1]);
      o[2 * p2] = (short)pr.x; o[2 * p2 + 1] = (short)pr.y;
    }
    *(short8*)&Bm[(((size_t)b * NCHK + chk) * 80 + row) * 64 + g * 8] = o;
  } else {
    int p = (blockIdx.x - PREP_BM_BLKS) * 256 + threadIdx.x;  // 0..73727
    int b = p / HW, px = p % HW;
    float nx = nrm[((size_t)b * 3 + 0) * HW + px];
    float ny = nrm[((size_t)b * 3 + 1) * HW + px];
    float nz = nrm[((size_t)b * 3 + 2) * HW + px];
    float mk = msk[(size_t)b * HW + px];
    // bias: -Cc (cos-1 shift) + mask fold (exp(-2000+..) == 0.f exactly)
    float bias = -Cc + (mk > 0.5f ? 0.f : -2000.f);
    *(float4*)&nv[(size_t)p * 4] = make_float4(Cc * nx, Cc * ny, Cc * nz, bias);
  }
}

// partial layout: part[ ks*PLANE + (b*NQP+q)*NCHA + ch ]
// 256 threads = 4 waves; wave w owns (M-half = w&1, K-half = (w>>1)*32); K-halves
// merged once at the end via LDS aliased onto the dead staging buffers.
template<int KSC>
__global__ __launch_bounds__(256, 4) void partial_kernel(
    const unsigned short* __restrict__ Bm,
    const float* __restrict__ nv,
    float* __restrict__ part)
{
  constexpr int SLICE  = HW / KSC;
  constexpr int NCHUNK = SLICE / 64;

  __shared__ __align__(16) unsigned short v_s[2][80][72];  // 23040 B (pad: 2-way free)
  __shared__ __align__(16) float nrm4_s[2][64][4];         // permuted (Cc*n, bias)

  // decode with XCD grouping: all 13 qt-blocks of a (b,ks) slice share blockIdx%8
  const int bx  = blockIdx.x;
  const int cls = bx & 7;
  const int r0  = bx >> 3;
  const int qt  = r0 % NQT;
  const int sh  = r0 / NQT;
  const int s   = sh * 8 + cls;       // slice id 0..2*KSC-1
  const int b   = s / KSC;
  const int ks  = s % KSC;

  const int t    = threadIdx.x;       // 0..255
  const int wv   = t >> 6;
  const int Mh   = wv & 1;            // M-half: queries 32*Mh..32*Mh+31
  const int kko  = (wv >> 1) * 32;    // K-half offset 0/32
  const int l    = t & 63;
  const int lq   = l >> 4;            // k-quad
  const int mrow = l & 15;

  // per-lane query geometry for this wave's two 16-row strips
  float qx[2], qy[2], qz[2];
  pix2qn(g_qtab.idx[qt * QT + 32 * Mh + mrow],      qx[0], qy[0], qz[0]);
  pix2qn(g_qtab.idx[qt * QT + 32 * Mh + 16 + mrow], qx[1], qy[1], qz[1]);

  // staging work split: thread t owns groups t, t+256, (t+512 if t<128) of 640
  const int g0r = t >> 3,          g0c = (t & 7) * 8;
  const int g1r = (t + 256) >> 3,  g1c = g0c;
  const int g2r = (t + 512) >> 3;  // valid if t < 128
  // bank-permuted px index for nrm4 writes: px' = 32*(px>>5)+4*(px&7)+((px>>3)&3)
  const int pxp = 32 * (l >> 5) + 4 * (l & 7) + ((l >> 3) & 3);

  f32x4 acc[2][5];
  #pragma unroll
  for (int h = 0; h < 2; ++h)
    #pragma unroll
    for (int nt = 0; nt < 5; ++nt) acc[h][nt] = (f32x4)(0.0f);

  short8 pB[3];
  float4 pnv;

  auto load_chunk = [&](int ck) {     // global -> registers (non-blocking)
    int chkAbs = ks * NCHUNK + ck;
    const unsigned short* src = Bm + ((size_t)b * NCHK + chkAbs) * (80 * 64);
    pB[0] = *(const short8*)(src + (size_t)(t)       * 8);
    pB[1] = *(const short8*)(src + (size_t)(t + 256) * 8);
    if (t < 128) pB[2] = *(const short8*)(src + (size_t)(t + 512) * 8);
    if (t < 64)  pnv = *(const float4*)&nv[((size_t)b * HW + chkAbs * 64 + l) * 4];
  };
  auto store_chunk = [&](int buf) {   // registers -> LDS (no conversion!)
    *(short8*)&v_s[buf][g0r][g0c] = pB[0];
    *(short8*)&v_s[buf][g1r][g1c] = pB[1];
    if (t < 128) *(short8*)&v_s[buf][g2r][g0c] = pB[2];
    if (t < 64)  *(float4*)&nrm4_s[buf][pxp][0] = pnv;
  };

  load_chunk(0);
  store_chunk(0);
  __syncthreads();

  for (int ck = 0; ck < NCHUNK; ++ck) {
    const int buf = ck & 1;
    if (ck + 1 < NCHUNK) load_chunk(ck + 1);   // overlap w/ compute below

    // ---- this wave's single K-half: 8 nv reads, 16 exps, 5 B reads, 10 MFMAs ----
    float e0[8], e1[8];
    #pragma unroll
    for (int j = 0; j < 8; ++j) {
      // px = kko + 8*lq + j  ->  permuted row kko + 4*j + lq (conflict-free b128)
      const float4 nvv = *(const float4*)&nrm4_s[buf][kko + 4 * j + lq][0];
      float t0 = fmaf(qx[0], nvv.x, fmaf(qy[0], nvv.y, fmaf(qz[0], nvv.z, nvv.w)));
      float t1 = fmaf(qx[1], nvv.x, fmaf(qy[1], nvv.y, fmaf(qz[1], nvv.z, nvv.w)));
      e0[j] = __expf(t0);
      e1[j] = __expf(t1);
    }
    short8 a0, a1;
    #pragma unroll
    for (int p = 0; p < 4; ++p) {
      ushort2 p0 = f2b2(e0[2 * p], e0[2 * p + 1]);
      ushort2 p1 = f2b2(e1[2 * p], e1[2 * p + 1]);
      a0[2 * p] = (short)p0.x; a0[2 * p + 1] = (short)p0.y;
      a1[2 * p] = (short)p1.x; a1[2 * p + 1] = (short)p1.y;
    }
    #pragma unroll
    for (int nt = 0; nt < 5; ++nt) {
      short8 bb = *(const short8*)&v_s[buf][16 * nt + mrow][kko + 8 * lq];
      acc[0][nt] = __builtin_amdgcn_mfma_f32_16x16x32_bf16(a0, bb, acc[0][nt], 0, 0, 0);
      acc[1][nt] = __builtin_amdgcn_mfma_f32_16x16x32_bf16(a1, bb, acc[1][nt], 0, 0, 0);
    }

    if (ck + 1 < NCHUNK) {
      store_chunk(buf ^ 1);
      __syncthreads();                 // single barrier per chunk
    }
  }

  // ---- merge K-halves through LDS (alias dead staging buffers), then epilogue ----
  __syncthreads();                     // all v_s reads done before aliasing
  float* scr = (float*)&v_s[0][0][0];  // [64 q][80 ch] f32 = 20480 B
  float* exs = scr + 64 * 80;          // [64 q][9]     f32 = 2304 B (fits in 25088)

  if (kko) {                           // waves 2,3: publish their half
    #pragma unroll
    for (int h = 0; h < 2; ++h)
      #pragma unroll
      for (int nt = 0; nt < 5; ++nt)
        #pragma unroll
        for (int rr = 0; rr < 4; ++rr) {
          int qloc = 32 * Mh + 16 * h + 4 * lq + rr;
          scr[qloc * 80 + 16 * nt + mrow] = acc[h][nt][rr];
        }
  }
  __syncthreads();
  const size_t pbase = (size_t)ks * PLANE + ((size_t)b * NQP + (size_t)(qt * QT)) * NCHA;
  if (!kko) {                          // waves 0,1: merge + write partials
    #pragma unroll
    for (int h = 0; h < 2; ++h) {
      #pragma unroll
      for (int nt = 0; nt < 5; ++nt)
        #pragma unroll
        for (int rr = 0; rr < 4; ++rr) {
          int qloc = 32 * Mh + 16 * h + 4 * lq + rr;
          acc[h][nt][rr] += scr[qloc * 80 + 16 * nt + mrow];
        }
      #pragma unroll
      for (int nt = 0; nt < 4; ++nt)
        #pragma unroll
        for (int rr = 0; rr < 4; ++rr) {
          int qloc = 32 * Mh + 16 * h + 4 * lq + rr;
          part[pbase + (size_t)qloc * NCHA + (size_t)(16 * nt + mrow)] = acc[h][nt][rr];
        }
      if (mrow < 7) {
        #pragma unroll
        for (int rr = 0; rr < 4; ++rr)
          exs[(32 * Mh + 16 * h + 4 * lq + rr) * 9 + mrow] = acc[h][4][rr];
      }
    }
  }
  __syncthreads();
  if (t < 64) {
    float gx, gy, gz;
    pix2qn(g_qtab.idx[qt * QT + t], gx, gy, gz);
    const float* E = exs + t * 9;
    float swc = gx * E[3] + gy * E[4] + gz * E[5];
    size_t o = pbase + (size_t)t * NCHA;
    part[o + 64] = E[0];
    part[o + 65] = E[1];
    part[o + 66] = E[2];
    part[o + 67] = swc;
    part[o + 68] = E[6];
  }
}

// single tail dispatch: blocks 0..207 reduce+normalize+scatter (8 queries each);
// blocks 208..415 zero-fill invalid-pixel output slots. No memsets needed.
#define NFIN (2 * NQT * 8)            // 208 finalize blocks
#define NTAIL (2 * NFIN)              // 416 total blocks

__global__ __launch_bounds__(256) void finalize_kernel(
    const float* __restrict__ part,
    float* __restrict__ out,
    int ksc)
{
  const int blk = blockIdx.x;
  const int t   = threadIdx.x;

  if (blk < NFIN) {
    __shared__ float sm[8][NCHA];     // 2.2 KB
    const int b   = blk / (NQT * 8);
    const int rem = blk % (NQT * 8);
    const int qt  = rem >> 3;
    const int qr  = rem & 7;          // eighth: queries qt*64 + qr*8 ..+7
    const int q0  = qt * QT + qr * 8;

    const size_t colbase = ((size_t)b * NQP + (size_t)q0) * NCHA;
    for (int i = t; i < 8 * NCHA; i += 256) {      // 552 sums, coalesced bursts
      float sv = 0.f;
      const size_t off = colbase + (size_t)i;
      #pragma unroll 8
      for (int k = 0; k < ksc; ++k) sv += part[(size_t)k * PLANE + off];
      sm[0][i] = sv;
    }
    __syncthreads();

    for (int i = t; i < 8 * NCHA; i += 256) {
      const int ql = i / NCHA;        // 0..7
      const int oc = i % NCHA;        // output channel
      const int pix = g_qtab.idx[q0 + ql];
      if (pix < 0) continue;
      const float* A = sm[ql];
      const float inv = 1.0f / (A[68] + 1e-9f);
      float gx, gy, gz;
      pix2qn(pix, gx, gy, gz);
      float val;
      if (oc == 0)      val = A[67] * inv;               // rm_cos
      else if (oc == 1) {                                // var
        val = 0.f;
        #pragma unroll
        for (int j = 0; j < 3; ++j) {
          float m  = A[61 + j] * inv;
          float sq = A[64 + j] * inv;
          val += sq - m * m;
        }
      }
      else if (oc == 2) val = gx;
      else if (oc == 3) val = gy;
      else if (oc == 4) val = gz;
      else              val = A[oc - 5] * inv;           // mapped features
      out[((size_t)b * NCHA + (size_t)oc) * 4096 + pix] = val;
    }
  } else {
    // zero-fill: all invalid-pixel slots across both batches (disjoint writes)
    const int start = (blk - NFIN) * 256 + t;
    const int strd  = (NTAIL - NFIN) * 256;
    const int TOT   = 2 * NCHA * 4096;
    for (int i = start; i < TOT; i += strd) {
      if (g_qtab.rank[i & 4095] < 0) out[i] = 0.0f;
    }
  }
}

extern "C" void kernel_launch(void* const* d_in, const int* in_sizes, int n_in,
                              void* d_out, int out_size, void* d_ws, size_t ws_size,
                              hipStream_t stream) {
  const float* fea = (const float*)d_in[0];
  const float* nrm = (const float*)d_in[1];
  const float* msk = (const float*)d_in[2];
  const float* lqn = (const float*)d_in[3];
  unsigned short* Bm = (unsigned short*)d_ws;
  float* nv   = (float*)((char*)d_ws + BM_BYTES);
  float* part = (float*)((char*)d_ws + PART_OFF);
  float* out  = (float*)d_out;

  prep_kernel<<<dim3(PREP_BM_BLKS + PREP_NV_BLKS), 256, 0, stream>>>(
      fea, nrm, msk, lqn, Bm, nv);

  const size_t need64 = PART_OFF + (size_t)PLANE * 64 * sizeof(float);  // 42.4 MB
  const size_t need32 = PART_OFF + (size_t)PLANE * 32 * sizeof(float);  // 27.7 MB
  if (ws_size >= need64) {            // 1664 blocks -> ~6 blocks/CU resident
    partial_kernel<64><<<dim3(2 * 64 * NQT), 256, 0, stream>>>(Bm, nv, part);
    finalize_kernel<<<dim3(NTAIL), 256, 0, stream>>>(part, out, 64);
  } else if (ws_size >= need32) {
    partial_kernel<32><<<dim3(2 * 32 * NQT), 256, 0, stream>>>(Bm, nv, part);
    finalize_kernel<<<dim3(NTAIL), 256, 0, stream>>>(part, out, 32);
  } else {
    partial_kernel<16><<<dim3(2 * 16 * NQT), 256, 0, stream>>>(Bm, nv, part);
    finalize_kernel<<<dim3(NTAIL), 256, 0, stream>>>(part, out, 16);
  }
}